// Round 2
// baseline (386.119 us; speedup 1.0000x reference)
//
#include <hip/hip_runtime.h>

// SortPooling: B=8192 graphs, spans of n in [32,96] rows over features
// (n_total x 128 fp32). Select top-K=30 rows per graph by last column
// (descending, stable ties by lower index), write full rows to out.
//
// Structure: ONE WAVE (64 lanes) per graph, 4 graphs per 256-thread block.
// No __syncthreads() anywhere — each wave is self-synchronized (LDS ops
// complete in order within a wave; __builtin_amdgcn_wave_barrier() is a
// zero-instruction compiler fence pinning phase order). Removes the
// vmcnt(0)/lgkmcnt(0) barrier drains, the 160-of-256 idle lanes in the
// rank phase, and all inter-wave phase coupling, so the CU scheduler can
// overlap one wave's cold key-load latency with another wave's
// gather/store traffic.
//
// Per wave:
//   phase 1: lanes load key[L] and key[L+64] (col-127, 512B-strided) -> LDS
//   phase 2: O(n^2) stable rank, each lane ranks elements L and L+64;
//            rank<K scatters the element index into sel[rank]
//   phase 3: 15 iterations of float4 gather (32 lanes = one 512B row) and
//            nontemporal store (output is streamed, never re-read ->
//            keep L2/L3 for the ~268MB feature array instead)

#define KSEL   30
#define MAXN   96
#define DIM    128
#define WPB    4                 // waves (graphs) per block
#define BLOCK  (WPB * 64)

typedef float f32x4 __attribute__((ext_vector_type(4)));

__global__ __launch_bounds__(BLOCK) void sortpool_kernel(
    const float* __restrict__ feat,
    const int*   __restrict__ gi,
    float*       __restrict__ out,
    const int    nb)
{
    __shared__ float key[WPB][MAXN];
    __shared__ int   sel[WPB][KSEL];

    const int t = (int)threadIdx.x;
    // t>>6 is wave-uniform; readfirstlane makes it an SGPR so gi loads scalarize
    const int w = __builtin_amdgcn_readfirstlane(t >> 6);
    const int L = t & 63;
    const int b = (int)blockIdx.x * WPB + w;
    if (b >= nb) return;                    // wave-uniform exit

    const int start = gi[2 * b];
    const int end   = gi[2 * b + 1];
    int n = end - start;
    if (n > MAXN) n = MAXN;

    if (L < KSEL) sel[w][L] = -1;           // guard: only matters if n < K (never here)

    // ---- phase 1: stage keys (each lane keeps its own keys in registers too)
    const bool v0 = (L < n);
    const bool v1 = (L + 64 < n);
    float k0 = 0.f, k1 = 0.f;
    if (v0) {
        k0 = feat[(size_t)(start + L) * DIM + (DIM - 1)];
        key[w][L] = k0;
    }
    if (v1) {
        k1 = feat[(size_t)(start + L + 64) * DIM + (DIM - 1)];
        key[w][L + 64] = k1;
    }
    __builtin_amdgcn_wave_barrier();        // compiler fence; HW LDS is in-order per wave

    // ---- phase 2: stable descending rank (all 64 lanes active)
    int r0 = 0, r1 = 0;
    #pragma unroll 4
    for (int j = 0; j < n; ++j) {
        const float kj = key[w][j];         // LDS broadcast read
        r0 += (int)((kj > k0) | ((kj == k0) & (j < L)));
        r1 += (int)((kj > k1) | ((kj == k1) & (j < L + 64)));
    }
    if (v0 && r0 < KSEL) sel[w][r0] = L;
    if (v1 && r1 < KSEL) sel[w][r1] = L + 64;
    __builtin_amdgcn_wave_barrier();

    // ---- phase 3: K*DIM/4 = 960 float4s per graph; 64 lanes -> 15 each.
    // 32 consecutive lanes cover one full 512B row (coalesced).
    const size_t out_base = (size_t)b * (KSEL * DIM);
    #pragma unroll 5
    for (int i = 0; i < (KSEL * (DIM / 4)) / 64; ++i) {   // 15 iterations
        const int e = i * 64 + L;
        const int k = e >> 5;               // which of the K rows
        const int c = (e & 31) << 2;        // float offset within row
        const int r = sel[w][k];            // LDS broadcast (uniform per half-wave)
        f32x4 v = (f32x4)(0.f);
        if (r >= 0)
            v = *(const f32x4*)&feat[(size_t)(start + r) * DIM + c];
        __builtin_nontemporal_store(v, (f32x4*)&out[out_base + (size_t)k * DIM + c]);
    }
}

extern "C" void kernel_launch(void* const* d_in, const int* in_sizes, int n_in,
                              void* d_out, int out_size, void* d_ws, size_t ws_size,
                              hipStream_t stream) {
    const float* feat = (const float*)d_in[0];
    const int*   gi   = (const int*)d_in[1];   // graph_indexes as int32 (x64 off)
    float*       out  = (float*)d_out;

    const int B = in_sizes[1] / 2;             // 8192 graphs
    const int grid = (B + WPB - 1) / WPB;      // 2048 blocks, 8 per CU
    sortpool_kernel<<<dim3(grid), dim3(BLOCK), 0, stream>>>(feat, gi, out, B);
}

// Round 3
// 373.425 us; speedup vs baseline: 1.0340x; 1.0340x over previous
//
#include <hip/hip_runtime.h>

// SortPooling: B=8192 graphs, spans of n in [32,96] rows over features
// (n_total x 128 fp32). Select top-K=30 rows per graph by last column
// (descending, stable ties by lower index), write full rows to out.
//
// One 256-thread block per graph:
//   phase 1: stage keys (strided col-127 reads) into LDS
//   phase 2: O(n^2) stable rank; rank<K scatters index into sel[rank]
//   phase 3: cooperative float4 copy of the K selected rows
//
// NOTE (session finding, R2): the bench's dur_us includes ~330 us of
// harness poison fills (2x ~1GiB fillBufferAligned at ~165 us each,
// 80%+ HBM peak). This kernel's own dispatch is ~42 us vs a ~45 us
// traffic floor (285 MB at 6.3 TB/s) — i.e. at the memory roofline.
// A wave-per-graph restructure with nontemporal stores measured ~14 us
// WORSE (R1/R2); reverted to this proven version.

#define KSEL   30
#define MAXN   96
#define DIM    128
#define BLOCK  256

__global__ __launch_bounds__(BLOCK) void sortpool_kernel(
    const float* __restrict__ feat,
    const int*   __restrict__ gi,
    float*       __restrict__ out)
{
    const int b = blockIdx.x;
    const int t = threadIdx.x;

    __shared__ float key[MAXN];
    __shared__ int   sel[KSEL];

    const int start = gi[2 * b];
    const int end   = gi[2 * b + 1];
    int n = end - start;
    if (n > MAXN) n = MAXN;

    if (t < KSEL) sel[t] = -1;          // guard: only matters if n < K (never here)
    if (t < n)
        key[t] = feat[(size_t)(start + t) * DIM + (DIM - 1)];
    __syncthreads();

    if (t < n) {
        const float ki = key[t];
        int rank = 0;
        #pragma unroll 4
        for (int j = 0; j < n; ++j) {
            const float kj = key[j];
            // stable descending rank: strictly greater, or equal with lower index
            rank += (kj > ki) || (kj == ki && j < t);
        }
        if (rank < KSEL) sel[rank] = t;
    }
    __syncthreads();

    // K*DIM/4 = 30*32 = 960 float4s per graph; 256 threads -> <=4 each.
    const size_t out_base = (size_t)b * (KSEL * DIM);
    for (int e = t; e < KSEL * (DIM / 4); e += BLOCK) {
        const int k = e >> 5;           // which of the K rows (32 float4 per row)
        const int c = (e & 31) << 2;    // float offset within row
        const int r = sel[k];
        float4 v;
        if (r >= 0) {
            v = *(const float4*)&feat[(size_t)(start + r) * DIM + c];
        } else {
            v = make_float4(0.f, 0.f, 0.f, 0.f);
        }
        *(float4*)&out[out_base + (size_t)k * DIM + c] = v;
    }
}

extern "C" void kernel_launch(void* const* d_in, const int* in_sizes, int n_in,
                              void* d_out, int out_size, void* d_ws, size_t ws_size,
                              hipStream_t stream) {
    const float* feat = (const float*)d_in[0];
    const int*   gi   = (const int*)d_in[1];   // graph_indexes as int32 (x64 off)
    float*       out  = (float*)d_out;

    const int B = in_sizes[1] / 2;             // 8192 graphs
    sortpool_kernel<<<dim3(B), dim3(BLOCK), 0, stream>>>(feat, gi, out);
}